// Round 1
// 536.031 us; speedup vs baseline: 1.0441x; 1.0441x over previous
//
#include <hip/hip_runtime.h>
#include <hip/hip_bf16.h>
#include <stdint.h>

// Problem constants
#define HGRID   16
#define WGRID   64
#define NTOK    1024      // HGRID*WGRID
#define BATCH   64
#define NHEADS  8
#define HDIM    64
#define DMODEL  512
#define BH_TOT  512       // BATCH*NHEADS
// HDIM^-0.5 * log2(e): q is pre-scaled so softmax uses exp2 directly.
#define QK_SCALE (0.125f * 1.44269504089f)

typedef __attribute__((ext_vector_type(8))) short short8;   // 8 x bf16 (4 VGPRs)
typedef __attribute__((ext_vector_type(4))) float floatx4;  // MFMA 16x16 accumulator

__device__ __forceinline__ short f2bf(float f) {
    union { float f; uint32_t u; } c{f};
    uint32_t r = (c.u + 0x7fffu + ((c.u >> 16) & 1u)) >> 16;  // RNE
    return (short)r;
}

// Async global->LDS, 16B per lane. LDS dest must be wave-uniform base + lane*16.
__device__ __forceinline__ void gload_lds16(const void* g, void* l) {
    auto gp = (const __attribute__((address_space(1))) void*)(uintptr_t)g;
    auto lp = (__attribute__((address_space(3))) void*)(uint32_t)(uintptr_t)l;
    __builtin_amdgcn_global_load_lds(gp, lp, 16, 0, 0);
}

// One half-tile stage share per thread: 2 x 16B (j=0 -> kh0 region, j=1 -> kh1).
__device__ __forceinline__ void stage2(const short* g, char* l) {
    gload_lds16(g, l);
    gload_lds16(g + 32, l + 8192);
}

// ---------------------------------------------------------------------------
// Kernel 1: fp32 -> bf16 elementwise cast (x). 8 elems/thread.
// ---------------------------------------------------------------------------
__global__ __launch_bounds__(256)
void cast_x_kernel(const float* __restrict__ in, short* __restrict__ out) {
    size_t i = (size_t)blockIdx.x * 256 + threadIdx.x;
    const float4* in4 = (const float4*)in;
    float4 a = in4[i * 2];
    float4 b = in4[i * 2 + 1];
    short8 o;
    o[0] = f2bf(a.x); o[1] = f2bf(a.y); o[2] = f2bf(a.z); o[3] = f2bf(a.w);
    o[4] = f2bf(b.x); o[5] = f2bf(b.y); o[6] = f2bf(b.z); o[7] = f2bf(b.w);
    *(short8*)(out + i * 8) = o;
}

// ---------------------------------------------------------------------------
// Kernel 2: fp32 [R][C] -> bf16 [C][R] transpose-cast (weights). 64x64 tiles.
// ---------------------------------------------------------------------------
__global__ __launch_bounds__(256)
void tcast_kernel(const float* __restrict__ in, short* __restrict__ out, int R, int C) {
    __shared__ short tile[64][72];
    int r0 = blockIdx.x * 64, c0 = blockIdx.y * 64;
    int t = threadIdx.x;
#pragma unroll
    for (int i = 0; i < 16; i++) {
        int s = i * 256 + t;
        int r = s >> 6, c = s & 63;
        tile[r][c] = f2bf(in[(size_t)(r0 + r) * C + c0 + c]);
    }
    __syncthreads();
#pragma unroll
    for (int i = 0; i < 16; i++) {
        int s = i * 256 + t;
        int c = s >> 6, r = s & 63;
        out[(size_t)(c0 + c) * R + r0 + r] = tile[r][c];
    }
}

// ---------------------------------------------------------------------------
// Kernel 3: bf16 GEMM, TN: C[M,N] = A[M,K=512] * B[N,K=512]^T.
// 256x256 tile, BK=64, 8 waves (2M x 4N), 128 KiB LDS, 8-phase schedule
// (T2 st_16x32 swizzle + T3/T4 counted vmcnt + T5 setprio), XCD-swizzled grid.
//
// LDS map (bytes): buf*65536 + isB*32768 + halfRow*16384 + kh*8192 + rr*64 + cc
//   (rr in [0,128) rows per half, kh = k-32-group, cc = byte col in [0,64))
// read swizzle: addr ^= ((addr>>9)&1)<<5  (bit9 == rr bit3)
// staging: linear LDS dest (global_load_lds), inverse-swizzled GLOBAL source.
//
// Stage stream (tile T, phases p0..p3):  p0: A(T+1)h0  p1: A(T+1)h1
//   p2: B(T+2)h0  p3: B(T+2)h1 ; s_waitcnt vmcnt(4) at end of p3 guarantees
//   tile T+1 fully landed (last 4 loads = the two B(T+2) stages may remain
//   in flight). A stages go to the non-compute buffer; B stages overwrite the
//   compute buffer's B region, which is only read at p0 (regs persist) and is
//   barrier-separated from the stage issue.
//
// MODE 0: qkv epilogue -> scatter q(*QK_SCALE)/k/v as [BH][NTOK][HDIM] bf16.
// MODE 1: proj epilogue -> fp32 out + bias, row-major [M][512].
// ---------------------------------------------------------------------------
template <int MODE>
__global__ __launch_bounds__(512, 2)
void gemm8_kernel(const short* __restrict__ A, const short* __restrict__ Bm,
                  short* __restrict__ qo, short* __restrict__ ko, short* __restrict__ vo,
                  float* __restrict__ outf, const float* __restrict__ bias) {
    constexpr int NBN = (MODE == 0) ? 6 : 2;       // 1536/256 or 512/256
    constexpr int NWG = (MODE == 0) ? 1536 : 512;  // total blocks (both %8==0)
    __shared__ short lds[65536];                   // 128 KiB
    char* ldsc = (char*)lds;

    // bijective XCD swizzle: consecutive in-XCD blocks share A panels
    int bid = blockIdx.x;
    bid = (bid & 7) * (NWG >> 3) + (bid >> 3);
    const int bn = bid % NBN, bm = bid / NBN;

    const int t = threadIdx.x;
    const int w = t >> 6, l = t & 63;
    const int lq = l & 15, quad = l >> 4;
    const int wm = w >> 2, wn = w & 3;             // 2 x 4 wave grid

    // ds_read lane addressing (swizzled)
    const int sw32 = ((lq >> 3) & 1) << 5;
    const int qb16 = (quad * 16) ^ sw32;
    const int a_lane = wm * 16384 + lq * 64 + qb16;
    const int b_lane = 32768 + (wn >> 1) * 16384 + (wn & 1) * 4096 + lq * 64 + qb16;
    const int t16 = t * 16;

    // staging lane addressing: LDS linear, global source inverse-swizzled
    const int srow = t >> 2;                                  // 0..127
    const int scol = ((t & 3) * 8) ^ (((t >> 5) & 1) << 4);   // shorts
    const short* gA = A + (size_t)bm * 256 * 512 + (size_t)srow * 512 + scol;
    const short* gB = Bm + (size_t)bn * 256 * 512 + (size_t)srow * 512 + scol;

    const floatx4 zero = {0.f, 0.f, 0.f, 0.f};
    floatx4 acc[8][4];
#pragma unroll
    for (int i = 0; i < 8; i++)
#pragma unroll
        for (int j = 0; j < 4; j++) acc[i][j] = zero;

    // ---- prologue: tile0 (A,B) + B(1); vmcnt(4) -> tile0 landed -----------
    stage2(gA,              ldsc + t16);                    // A0 h0 -> buf0
    stage2(gA + 65536,      ldsc + 16384 + t16);            // A0 h1
    stage2(gB,              ldsc + 32768 + t16);            // B0 h0
    stage2(gB + 65536,      ldsc + 49152 + t16);            // B0 h1
    stage2(gB + 64,         ldsc + 98304 + t16);            // B1 h0 -> buf1
    stage2(gB + 65536 + 64, ldsc + 114688 + t16);           // B1 h1
    asm volatile("s_waitcnt vmcnt(4)" ::: "memory");
    __builtin_amdgcn_s_barrier();

#pragma unroll 2
    for (int T = 0; T < 8; ++T) {
        const int bo  = (T & 1) << 16;   // compute buffer base
        const int nbo = bo ^ 65536;      // other buffer
        short8 bfr[4][2];                // B frags persist across the 4 phases

        // ---- phase 0: read B(all) + A q0; stage A(T+1)h0 ----
        {
            short8 af[2][2];
#pragma unroll
            for (int ni = 0; ni < 4; ni++)
#pragma unroll
                for (int kh = 0; kh < 2; kh++)
                    bfr[ni][kh] = *(const short8*)(ldsc + bo + b_lane + ni * 1024 + kh * 8192);
#pragma unroll
            for (int m2 = 0; m2 < 2; m2++)
#pragma unroll
                for (int kh = 0; kh < 2; kh++)
                    af[m2][kh] = *(const short8*)(ldsc + bo + a_lane + m2 * 1024 + kh * 8192);
            if (T < 7) stage2(gA + (T + 1) * 64, ldsc + nbo + t16);
            __builtin_amdgcn_sched_barrier(0);
            __builtin_amdgcn_s_barrier();
            asm volatile("s_waitcnt lgkmcnt(0)" ::: "memory");
            __builtin_amdgcn_sched_barrier(0);
            __builtin_amdgcn_s_setprio(1);
#pragma unroll
            for (int kh = 0; kh < 2; kh++)
#pragma unroll
                for (int m2 = 0; m2 < 2; m2++)
#pragma unroll
                    for (int ni = 0; ni < 4; ni++)
                        acc[m2][ni] = __builtin_amdgcn_mfma_f32_16x16x32_bf16(
                            af[m2][kh], bfr[ni][kh], acc[m2][ni], 0, 0, 0);
            __builtin_amdgcn_s_setprio(0);
            __builtin_amdgcn_sched_barrier(0);
            __builtin_amdgcn_s_barrier();
        }
        // ---- phase 1: read A q1; stage A(T+1)h1 ----
        {
            short8 af[2][2];
#pragma unroll
            for (int m2 = 0; m2 < 2; m2++)
#pragma unroll
                for (int kh = 0; kh < 2; kh++)
                    af[m2][kh] = *(const short8*)(ldsc + bo + a_lane + (2 + m2) * 1024 + kh * 8192);
            if (T < 7) stage2(gA + 65536 + (T + 1) * 64, ldsc + nbo + 16384 + t16);
            __builtin_amdgcn_sched_barrier(0);
            __builtin_amdgcn_s_barrier();
            asm volatile("s_waitcnt lgkmcnt(0)" ::: "memory");
            __builtin_amdgcn_sched_barrier(0);
            __builtin_amdgcn_s_setprio(1);
#pragma unroll
            for (int kh = 0; kh < 2; kh++)
#pragma unroll
                for (int m2 = 0; m2 < 2; m2++)
#pragma unroll
                    for (int ni = 0; ni < 4; ni++)
                        acc[2 + m2][ni] = __builtin_amdgcn_mfma_f32_16x16x32_bf16(
                            af[m2][kh], bfr[ni][kh], acc[2 + m2][ni], 0, 0, 0);
            __builtin_amdgcn_s_setprio(0);
            __builtin_amdgcn_sched_barrier(0);
            __builtin_amdgcn_s_barrier();
        }
        // ---- phase 2: read A q2; stage B(T+2)h0 (into compute buffer, B dead) ----
        {
            short8 af[2][2];
#pragma unroll
            for (int m2 = 0; m2 < 2; m2++)
#pragma unroll
                for (int kh = 0; kh < 2; kh++)
                    af[m2][kh] = *(const short8*)(ldsc + bo + a_lane + (4 + m2) * 1024 + kh * 8192);
            if (T < 6) stage2(gB + (T + 2) * 64, ldsc + bo + 32768 + t16);
            __builtin_amdgcn_sched_barrier(0);
            __builtin_amdgcn_s_barrier();
            asm volatile("s_waitcnt lgkmcnt(0)" ::: "memory");
            __builtin_amdgcn_sched_barrier(0);
            __builtin_amdgcn_s_setprio(1);
#pragma unroll
            for (int kh = 0; kh < 2; kh++)
#pragma unroll
                for (int m2 = 0; m2 < 2; m2++)
#pragma unroll
                    for (int ni = 0; ni < 4; ni++)
                        acc[4 + m2][ni] = __builtin_amdgcn_mfma_f32_16x16x32_bf16(
                            af[m2][kh], bfr[ni][kh], acc[4 + m2][ni], 0, 0, 0);
            __builtin_amdgcn_s_setprio(0);
            __builtin_amdgcn_sched_barrier(0);
            __builtin_amdgcn_s_barrier();
        }
        // ---- phase 3: read A q3; stage B(T+2)h1; counted vmcnt; tile boundary ----
        {
            short8 af[2][2];
#pragma unroll
            for (int m2 = 0; m2 < 2; m2++)
#pragma unroll
                for (int kh = 0; kh < 2; kh++)
                    af[m2][kh] = *(const short8*)(ldsc + bo + a_lane + (6 + m2) * 1024 + kh * 8192);
            if (T < 6) stage2(gB + 65536 + (T + 2) * 64, ldsc + bo + 49152 + t16);
            __builtin_amdgcn_sched_barrier(0);
            __builtin_amdgcn_s_barrier();
            asm volatile("s_waitcnt lgkmcnt(0)" ::: "memory");
            __builtin_amdgcn_sched_barrier(0);
            __builtin_amdgcn_s_setprio(1);
#pragma unroll
            for (int kh = 0; kh < 2; kh++)
#pragma unroll
                for (int m2 = 0; m2 < 2; m2++)
#pragma unroll
                    for (int ni = 0; ni < 4; ni++)
                        acc[6 + m2][ni] = __builtin_amdgcn_mfma_f32_16x16x32_bf16(
                            af[m2][kh], bfr[ni][kh], acc[6 + m2][ni], 0, 0, 0);
            __builtin_amdgcn_s_setprio(0);
            __builtin_amdgcn_sched_barrier(0);
            if (T < 6) asm volatile("s_waitcnt vmcnt(4)" ::: "memory");
            else       asm volatile("s_waitcnt vmcnt(0)" ::: "memory");
            __builtin_amdgcn_s_barrier();
        }
    }

    // ---- epilogue. C/D layout: col = lane&15, row = (lane>>4)*4 + reg ----
    if (MODE == 0) {
#pragma unroll
        for (int mi = 0; mi < 8; mi++)
#pragma unroll
            for (int ni = 0; ni < 4; ni++) {
                int col = bn * 256 + wn * 64 + ni * 16 + lq;
                int which = col >> 9, hd = (col >> 6) & 7, dd = col & 63;
#pragma unroll
                for (int r = 0; r < 4; r++) {
                    int row = bm * 256 + wm * 128 + mi * 16 + quad * 4 + r;
                    int bidx = row >> 10, tok = row & 1023;
                    size_t didx = (((size_t)bidx * NHEADS + hd) * NTOK + tok) * HDIM + dd;
                    float val = acc[mi][ni][r];
                    if (which == 0)       qo[didx] = f2bf(val * QK_SCALE);
                    else if (which == 1)  ko[didx] = f2bf(val);
                    else                  vo[didx] = f2bf(val);
                }
            }
    } else {
#pragma unroll
        for (int ni = 0; ni < 4; ni++) {
            int col = bn * 256 + wn * 64 + ni * 16 + lq;
            float bv = bias[col];
#pragma unroll
            for (int mi = 0; mi < 8; mi++)
#pragma unroll
                for (int r = 0; r < 4; r++) {
                    int row = bm * 256 + wm * 128 + mi * 16 + quad * 4 + r;
                    outf[(size_t)row * DMODEL + col] = acc[mi][ni][r] + bv;
                }
        }
    }
}

// ---------------------------------------------------------------------------
// Kernel 4: bf16 transpose v [BH][NTOK][HDIM] -> vT [BH][HDIM][NTOK].
// ---------------------------------------------------------------------------
__global__ __launch_bounds__(256)
void tv_kernel(const short* __restrict__ v, short* __restrict__ vT) {
    __shared__ short tile[64][72];
    int tt = blockIdx.x;
    int bh = blockIdx.y;
    int t = threadIdx.x;
    const short* src = v + ((size_t)bh * NTOK + tt * 64) * HDIM;
#pragma unroll
    for (int i = 0; i < 2; i++) {
        int s = i * 256 + t;
        int r = s >> 3, c8 = (s & 7) * 8;
        *(short8*)&tile[r][c8] = *(const short8*)(src + r * HDIM + c8);
    }
    __syncthreads();
    short* dst = vT + (size_t)bh * HDIM * NTOK + tt * 64;
#pragma unroll
    for (int i = 0; i < 2; i++) {
        int s = i * 256 + t;
        int d = s & 63, t0 = (s >> 6) * 8;
        short8 g;
#pragma unroll
        for (int j = 0; j < 8; j++) g[j] = tile[t0 + j][d];
        *(short8*)(dst + (size_t)d * NTOK + t0) = g;
    }
}

// ---------------------------------------------------------------------------
// Kernel 5: local-window attention, v2 (unchanged).
// ---------------------------------------------------------------------------
__global__ __launch_bounds__(256)
void attn_kernel(const short* __restrict__ q, const short* __restrict__ k,
                 const short* __restrict__ vT, short* __restrict__ ao) {
    const int bid = blockIdx.x;
    const int h = (bid >> 3) & 15;
    const int bh = (bid & 7) + 8 * (bid >> 7);
    const int b = bh >> 3, head = bh & 7;
    const int t = threadIdx.x;
    const int w = t >> 6;
    const int l = t & 63;
    const int lq = l & 15, quad = l >> 4;

    __shared__ short Kc[64][72];      // [kw][d]
    __shared__ short Vc[80][72];      // [d][kw]; row 64 = ones; 65..79 never read back
    __shared__ short Pc[4][16][40];   // per-wave [q][kw_local 0..31], stride 40

    const int s_w = (w == 0) ? 0 : (w == 1) ? 8 : (w == 2) ? 24 : 32;

    const short* qbp = q + ((size_t)bh * NTOK + h * 64 + w * 16 + lq) * HDIM + quad * 8;
    short8 qa0 = *(const short8*)(qbp);
    short8 qa1 = *(const short8*)(qbp + 32);

    bool ok[2][4];
#pragma unroll
    for (int nt = 0; nt < 2; nt++)
#pragma unroll
        for (int r = 0; r < 4; r++) {
            int kw_g = s_w + nt * 16 + lq;
            int qi = w * 16 + quad * 4 + r;
            int dw = kw_g - qi;
            ok[nt][r] = (dw <= 5) && (dw >= -5);
        }

    const floatx4 zero = {0.f, 0.f, 0.f, 0.f};
    floatx4 O[5];
#pragma unroll
    for (int i = 0; i < 5; i++) O[i] = zero;

    if (t < 64) Vc[64][t] = (short)0x3F80;

    const int kh0 = (h - 3 < 0) ? 0 : h - 3;
    const int kh1 = (h + 3 > HGRID - 1) ? HGRID - 1 : h + 3;

    for (int kh = kh0; kh <= kh1; ++kh) {
        __syncthreads();
        {
            const short* kb = k + ((size_t)bh * NTOK + kh * 64) * HDIM;
            const short* vb = vT + (size_t)bh * HDIM * NTOK + kh * 64;
#pragma unroll
            for (int i = 0; i < 2; i++) {
                int s = i * 256 + t;
                int r = s >> 3, c8 = (s & 7) * 8;
                *(short8*)&Kc[r][c8] = *(const short8*)(kb + r * HDIM + c8);
                *(short8*)&Vc[r][c8] = *(const short8*)(vb + (size_t)r * NTOK + c8);
            }
        }
        __syncthreads();

        floatx4 S[2];
#pragma unroll
        for (int nt = 0; nt < 2; nt++) {
            S[nt] = zero;
            short8 b0 = *(const short8*)&Kc[s_w + nt * 16 + lq][quad * 8];
            short8 b1 = *(const short8*)&Kc[s_w + nt * 16 + lq][quad * 8 + 32];
            S[nt] = __builtin_amdgcn_mfma_f32_16x16x32_bf16(qa0, b0, S[nt], 0, 0, 0);
            S[nt] = __builtin_amdgcn_mfma_f32_16x16x32_bf16(qa1, b1, S[nt], 0, 0, 0);
        }

#pragma unroll
        for (int nt = 0; nt < 2; nt++)
#pragma unroll
            for (int r = 0; r < 4; r++) {
                float p = ok[nt][r] ? exp2f(S[nt][r]) : 0.f;
                Pc[w][quad * 4 + r][nt * 16 + lq] = f2bf(p);
            }

        short8 pa = *(const short8*)&Pc[w][lq][quad * 8];
#pragma unroll
        for (int dt = 0; dt < 5; dt++) {
            short8 vf = *(const short8*)&Vc[dt * 16 + lq][s_w + quad * 8];
            O[dt] = __builtin_amdgcn_mfma_f32_16x16x32_bf16(pa, vf, O[dt], 0, 0, 0);
        }
    }

    float inv[4];
#pragma unroll
    for (int r = 0; r < 4; r++) {
        float s = __shfl(O[4][r], l & 48);
        inv[r] = 1.0f / s;
    }

#pragma unroll
    for (int dt = 0; dt < 4; dt++)
#pragma unroll
        for (int r = 0; r < 4; r++) {
            int qi = w * 16 + quad * 4 + r;
            int d = dt * 16 + lq;
            float o = O[dt][r] * inv[r];
            ao[((size_t)b * NTOK + h * 64 + qi) * DMODEL + head * HDIM + d] = f2bf(o);
        }
}

// ---------------------------------------------------------------------------
extern "C" void kernel_launch(void* const* d_in, const int* in_sizes, int n_in,
                              void* d_out, int out_size, void* d_ws, size_t ws_size,
                              hipStream_t stream) {
    const float* x      = (const float*)d_in[0];
    const float* w_qkv  = (const float*)d_in[1];
    const float* w_proj = (const float*)d_in[2];
    const float* b_proj = (const float*)d_in[3];
    float* out = (float*)d_out;

    const size_t SZ_X    = (size_t)BATCH * NTOK * DMODEL * 2;
    const size_t SZ_HEAD = (size_t)BH_TOT * NTOK * HDIM * 2;
    char* p = (char*)d_ws;
    short* xb     = (short*)p; p += SZ_X;
    short* wqkvT  = (short*)p; p += (size_t)1536 * 512 * 2;
    short* wprojT = (short*)p; p += (size_t)512 * 512 * 2;
    short* qb     = (short*)p; p += SZ_HEAD;
    short* kb     = (short*)p; p += SZ_HEAD;
    short* vb     = (short*)p; p += SZ_HEAD;
    short* vTb    = (short*)p; p += SZ_HEAD;
    short* ao     = xb;  // alias: xb dead after gemm8<0>

    cast_x_kernel<<<dim3((BATCH * NTOK * DMODEL) / (256 * 8)), dim3(256), 0, stream>>>(x, xb);
    tcast_kernel<<<dim3(512 / 64, 1536 / 64), dim3(256), 0, stream>>>(w_qkv, wqkvT, 512, 1536);
    tcast_kernel<<<dim3(512 / 64, 512 / 64), dim3(256), 0, stream>>>(w_proj, wprojT, 512, 512);
    gemm8_kernel<0><<<dim3(1536), dim3(512), 0, stream>>>(xb, wqkvT, qb, kb, vb, nullptr, nullptr);
    tv_kernel<<<dim3(NTOK / 64, BH_TOT), dim3(256), 0, stream>>>(vb, vTb);
    attn_kernel<<<dim3(HGRID * BH_TOT), dim3(256), 0, stream>>>(qb, kb, vTb, ao);
    gemm8_kernel<1><<<dim3(512), dim3(512), 0, stream>>>(ao, wprojT, nullptr, nullptr, nullptr, out, b_proj);
}

// Round 2
// 481.536 us; speedup vs baseline: 1.1622x; 1.1132x over previous
//
#include <hip/hip_runtime.h>
#include <hip/hip_bf16.h>
#include <stdint.h>

// Problem constants
#define HGRID   16
#define WGRID   64
#define NTOK    1024      // HGRID*WGRID
#define BATCH   64
#define NHEADS  8
#define HDIM    64
#define DMODEL  512
#define BH_TOT  512       // BATCH*NHEADS
// HDIM^-0.5 * log2(e): q is pre-scaled so softmax uses exp2 directly.
#define QK_SCALE (0.125f * 1.44269504089f)

typedef __attribute__((ext_vector_type(8))) short short8;   // 8 x bf16 (4 VGPRs)
typedef __attribute__((ext_vector_type(4))) float floatx4;  // MFMA 16x16 accumulator

__device__ __forceinline__ short f2bf(float f) {
    union { float f; uint32_t u; } c{f};
    uint32_t r = (c.u + 0x7fffu + ((c.u >> 16) & 1u)) >> 16;  // RNE
    return (short)r;
}

// Async global->LDS, 16B per lane. LDS dest must be wave-uniform base + lane*16.
__device__ __forceinline__ void gload_lds16(const void* g, void* l) {
    auto gp = (const __attribute__((address_space(1))) void*)(uintptr_t)g;
    auto lp = (__attribute__((address_space(3))) void*)(uint32_t)(uintptr_t)l;
    __builtin_amdgcn_global_load_lds(gp, lp, 16, 0, 0);
}

// ---------------------------------------------------------------------------
// Kernel 1: fp32 -> bf16 elementwise cast (x). 8 elems/thread.
// ---------------------------------------------------------------------------
__global__ __launch_bounds__(256)
void cast_x_kernel(const float* __restrict__ in, short* __restrict__ out) {
    size_t i = (size_t)blockIdx.x * 256 + threadIdx.x;
    const float4* in4 = (const float4*)in;
    float4 a = in4[i * 2];
    float4 b = in4[i * 2 + 1];
    short8 o;
    o[0] = f2bf(a.x); o[1] = f2bf(a.y); o[2] = f2bf(a.z); o[3] = f2bf(a.w);
    o[4] = f2bf(b.x); o[5] = f2bf(b.y); o[6] = f2bf(b.z); o[7] = f2bf(b.w);
    *(short8*)(out + i * 8) = o;
}

// ---------------------------------------------------------------------------
// Kernel 2: fp32 [R][C] -> bf16 [C][R] transpose-cast (weights). 64x64 tiles.
// ---------------------------------------------------------------------------
__global__ __launch_bounds__(256)
void tcast_kernel(const float* __restrict__ in, short* __restrict__ out, int R, int C) {
    __shared__ short tile[64][72];
    int r0 = blockIdx.x * 64, c0 = blockIdx.y * 64;
    int t = threadIdx.x;
#pragma unroll
    for (int i = 0; i < 16; i++) {
        int s = i * 256 + t;
        int r = s >> 6, c = s & 63;
        tile[r][c] = f2bf(in[(size_t)(r0 + r) * C + c0 + c]);
    }
    __syncthreads();
#pragma unroll
    for (int i = 0; i < 16; i++) {
        int s = i * 256 + t;
        int c = s >> 6, r = s & 63;
        out[(size_t)(c0 + c) * R + r0 + r] = tile[r][c];
    }
}

// ---------------------------------------------------------------------------
// Kernel 3: bf16 GEMM, TN: C[M,N] = A[M,K=512] * B[N,K=512]^T.
// 128x256 tile, BK=32, 8 waves (2M x 4N), 3-deep LDS ring (24 KB/buf = 72 KB)
// -> 2 blocks/CU (16 waves/CU): one block's prologue/epilogue hides under the
// other's MFMA. One barrier per K-tile, counted vmcnt(3) (3 loads/tile).
//
// LDS buffer map (24 KB): A [128 rows][4 slots x 16B] at 0, B [256 rows][4
// slots] at +8192. Slot swizzle: logical slot s stored at phys s^((row>>1)&3)
// -> frag ds_read_b128 2-way banks (free). Staged with linear LDS dest +
// inverse-swizzled global source column.
//
// Ring schedule (tile T, bufs mod 3): stage(T+2)->buf[(T+2)%3] issued FIRST
// (that buf was last read at iter T-1, all waves past its barrier); read 8
// frags from buf[T%3]; lgkmcnt(0); 16 MFMA; vmcnt(3) => tile T+1 landed;
// s_barrier. Never drains vmcnt to 0 until the tail.
//
// MODE 0 epilogue (which = bn>>1 is block-uniform):
//   q (bn 0,1): scatter *QK_SCALE -> [BH][NTOK][HDIM] bf16
//   k (bn 2,3): scatter         -> [BH][NTOK][HDIM] bf16
//   v (bn 4,5): LDS-transpose the 128x256 chunk -> vT [BH][HDIM][NTOK]
//               (coalesced 16B stores; replaces the old tv_kernel)
// MODE 1: proj epilogue -> fp32 out + bias, row-major [M][512].
// ---------------------------------------------------------------------------
template <int MODE>
__global__ __launch_bounds__(512, 4)
void gemm_kernel(const short* __restrict__ A, const short* __restrict__ Bm,
                 short* __restrict__ qo, short* __restrict__ ko, short* __restrict__ vTo,
                 float* __restrict__ outf, const float* __restrict__ bias) {
    constexpr int NBN = (MODE == 0) ? 6 : 2;       // 1536/256 or 512/256
    constexpr int NWG = (MODE == 0) ? 3072 : 1024; // 512*NBN (both %8==0)
    __shared__ char lds[73728];                    // 3 x 24 KB ring; v-transpose overlay
    char* ldsc = (char*)lds;

    // bijective XCD swizzle: consecutive in-XCD blocks share an A panel
    int bid = blockIdx.x;
    bid = (bid & 7) * (NWG >> 3) + (bid >> 3);
    const int bn = bid % NBN, bm = bid / NBN;

    const int t = threadIdx.x;
    const int w = t >> 6, l = t & 63;
    const int lq = l & 15, quad = l >> 4;
    const int wm = w >> 2, wn = w & 3;             // 2 x 4 wave grid

    // frag LDS byte offsets within a buffer (swizzled read)
    const int sw = ((quad ^ ((lq >> 1) & 3)) << 4);
    const int a_off = (wm * 64 + lq) * 64 + sw;            // + mi*1024
    const int b_off = 8192 + (wn * 64 + lq) * 64 + sw;     // + ni*1024

    // staging: linear LDS dest, inverse-swizzled global source column
    const int srow = t >> 2;                                   // 0..127
    const int scol = ((t & 3) ^ ((t >> 3) & 3)) * 8;           // shorts
    const short* sA = A + (size_t)bm * 128 * 512 + (size_t)srow * 512 + scol;
    const short* sB = Bm + (size_t)bn * 256 * 512 + (size_t)srow * 512 + scol;
    const int t16 = t * 16;

    const floatx4 zero = {0.f, 0.f, 0.f, 0.f};
    floatx4 acc[4][4];
#pragma unroll
    for (int i = 0; i < 4; i++)
#pragma unroll
        for (int j = 0; j < 4; j++) acc[i][j] = zero;

#define STAGE(T, BUFI) do {                                            \
        char* _b = ldsc + (BUFI) * 24576;                              \
        gload_lds16(sA + (T) * 32, _b + t16);                          \
        gload_lds16(sB + (T) * 32, _b + 8192 + t16);                   \
        gload_lds16(sB + 128 * 512 + (T) * 32, _b + 16384 + t16);      \
    } while (0)

    // ---- prologue: tiles 0,1 in flight; tile0 landed after vmcnt(3) ----
    STAGE(0, 0);
    STAGE(1, 1);
    asm volatile("s_waitcnt vmcnt(3)" ::: "memory");
    __builtin_amdgcn_s_barrier();

#pragma unroll
    for (int T = 0; T < 16; ++T) {
        const int cur = T % 3;
        if (T + 2 < 16) STAGE(T + 2, (T + 2) % 3);   // dead buffer (read at T-1)

        const char* base = ldsc + cur * 24576;
        short8 af[4], bfr[4];
#pragma unroll
        for (int mi = 0; mi < 4; mi++)
            af[mi] = *(const short8*)(base + a_off + mi * 1024);
#pragma unroll
        for (int ni = 0; ni < 4; ni++)
            bfr[ni] = *(const short8*)(base + b_off + ni * 1024);
        asm volatile("s_waitcnt lgkmcnt(0)" ::: "memory");
        __builtin_amdgcn_sched_barrier(0);
        __builtin_amdgcn_s_setprio(1);
#pragma unroll
        for (int mi = 0; mi < 4; mi++)
#pragma unroll
            for (int ni = 0; ni < 4; ni++)
                acc[mi][ni] = __builtin_amdgcn_mfma_f32_16x16x32_bf16(
                    af[mi], bfr[ni], acc[mi][ni], 0, 0, 0);
        __builtin_amdgcn_s_setprio(0);
        __builtin_amdgcn_sched_barrier(0);
        if (T < 14) asm volatile("s_waitcnt vmcnt(3)" ::: "memory");  // tile T+1 landed
        else        asm volatile("s_waitcnt vmcnt(0)" ::: "memory");
        __builtin_amdgcn_s_barrier();
    }
#undef STAGE

    // ---- epilogue. C/D layout: col = lane&15, row = (lane>>4)*4 + reg ----
    if (MODE == 1) {
#pragma unroll
        for (int ni = 0; ni < 4; ni++) {
            int col = bn * 256 + wn * 64 + ni * 16 + lq;
            float bv = bias[col];
#pragma unroll
            for (int mi = 0; mi < 4; mi++)
#pragma unroll
                for (int r = 0; r < 4; r++) {
                    int row = bm * 128 + wm * 64 + mi * 16 + quad * 4 + r;
                    outf[(size_t)row * DMODEL + col] = acc[mi][ni][r] + bv;
                }
        }
        return;
    }

    const int which = bn >> 1;           // 0=q, 1=k, 2=v — block-uniform
    if (which < 2) {
        short* dst = which ? ko : qo;
        const float sc = which ? 1.0f : QK_SCALE;
        const int hd = (bn & 1) * 4 + wn;
#pragma unroll
        for (int mi = 0; mi < 4; mi++)
#pragma unroll
            for (int ni = 0; ni < 4; ni++)
#pragma unroll
                for (int r = 0; r < 4; r++) {
                    int row = bm * 128 + wm * 64 + mi * 16 + quad * 4 + r;
                    int tok = row & 1023, bidx = row >> 10;
                    dst[(((size_t)bidx * NHEADS + hd) * NTOK + tok) * HDIM + ni * 16 + lq] =
                        f2bf(acc[mi][ni][r] * sc);
                }
    } else {
        // v: transpose 128 rows x 256 cols through LDS, write vT coalesced.
        short* Tb = (short*)ldsc;        // [256 cols][140] (pad: 70 dwords, 2-way banks)
        __syncthreads();
#pragma unroll
        for (int mi = 0; mi < 4; mi++)
#pragma unroll
            for (int ni = 0; ni < 4; ni++) {
                int cl = wn * 64 + ni * 16 + lq;
#pragma unroll
                for (int rp = 0; rp < 2; rp++) {
                    int rw = wm * 64 + mi * 16 + quad * 4 + rp * 2;
                    uint32_t lo = (uint32_t)(uint16_t)f2bf(acc[mi][ni][rp * 2]);
                    uint32_t hi = (uint32_t)(uint16_t)f2bf(acc[mi][ni][rp * 2 + 1]);
                    *(uint32_t*)&Tb[cl * 140 + rw] = lo | (hi << 16);
                }
            }
        __syncthreads();
        int cl = t >> 1, part = t & 1;
        int hd = (bn & 1) * 4 + (cl >> 6), dd = cl & 63;
        int bidx = bm >> 3, tokb = (bm & 7) * 128 + part * 64;
        short* dst = vTo + (((size_t)bidx * NHEADS + hd) * HDIM + dd) * NTOK + tokb;
#pragma unroll
        for (int j = 0; j < 8; j++) {
            uint2 x = *(const uint2*)&Tb[cl * 140 + part * 64 + j * 8];
            uint2 y = *(const uint2*)&Tb[cl * 140 + part * 64 + j * 8 + 4];
            uint4 o; o.x = x.x; o.y = x.y; o.z = y.x; o.w = y.y;
            *(uint4*)(dst + j * 8) = o;
        }
    }
}

// ---------------------------------------------------------------------------
// Kernel 5: local-window attention, v2 (unchanged).
// ---------------------------------------------------------------------------
__global__ __launch_bounds__(256)
void attn_kernel(const short* __restrict__ q, const short* __restrict__ k,
                 const short* __restrict__ vT, short* __restrict__ ao) {
    const int bid = blockIdx.x;
    const int h = (bid >> 3) & 15;
    const int bh = (bid & 7) + 8 * (bid >> 7);
    const int b = bh >> 3, head = bh & 7;
    const int t = threadIdx.x;
    const int w = t >> 6;
    const int l = t & 63;
    const int lq = l & 15, quad = l >> 4;

    __shared__ short Kc[64][72];      // [kw][d]
    __shared__ short Vc[80][72];      // [d][kw]; row 64 = ones; 65..79 never read back
    __shared__ short Pc[4][16][40];   // per-wave [q][kw_local 0..31], stride 40

    const int s_w = (w == 0) ? 0 : (w == 1) ? 8 : (w == 2) ? 24 : 32;

    const short* qbp = q + ((size_t)bh * NTOK + h * 64 + w * 16 + lq) * HDIM + quad * 8;
    short8 qa0 = *(const short8*)(qbp);
    short8 qa1 = *(const short8*)(qbp + 32);

    bool ok[2][4];
#pragma unroll
    for (int nt = 0; nt < 2; nt++)
#pragma unroll
        for (int r = 0; r < 4; r++) {
            int kw_g = s_w + nt * 16 + lq;
            int qi = w * 16 + quad * 4 + r;
            int dw = kw_g - qi;
            ok[nt][r] = (dw <= 5) && (dw >= -5);
        }

    const floatx4 zero = {0.f, 0.f, 0.f, 0.f};
    floatx4 O[5];
#pragma unroll
    for (int i = 0; i < 5; i++) O[i] = zero;

    if (t < 64) Vc[64][t] = (short)0x3F80;

    const int kh0 = (h - 3 < 0) ? 0 : h - 3;
    const int kh1 = (h + 3 > HGRID - 1) ? HGRID - 1 : h + 3;

    for (int kh = kh0; kh <= kh1; ++kh) {
        __syncthreads();
        {
            const short* kb = k + ((size_t)bh * NTOK + kh * 64) * HDIM;
            const short* vb = vT + (size_t)bh * HDIM * NTOK + kh * 64;
#pragma unroll
            for (int i = 0; i < 2; i++) {
                int s = i * 256 + t;
                int r = s >> 3, c8 = (s & 7) * 8;
                *(short8*)&Kc[r][c8] = *(const short8*)(kb + r * HDIM + c8);
                *(short8*)&Vc[r][c8] = *(const short8*)(vb + (size_t)r * NTOK + c8);
            }
        }
        __syncthreads();

        floatx4 S[2];
#pragma unroll
        for (int nt = 0; nt < 2; nt++) {
            S[nt] = zero;
            short8 b0 = *(const short8*)&Kc[s_w + nt * 16 + lq][quad * 8];
            short8 b1 = *(const short8*)&Kc[s_w + nt * 16 + lq][quad * 8 + 32];
            S[nt] = __builtin_amdgcn_mfma_f32_16x16x32_bf16(qa0, b0, S[nt], 0, 0, 0);
            S[nt] = __builtin_amdgcn_mfma_f32_16x16x32_bf16(qa1, b1, S[nt], 0, 0, 0);
        }

#pragma unroll
        for (int nt = 0; nt < 2; nt++)
#pragma unroll
            for (int r = 0; r < 4; r++) {
                float p = ok[nt][r] ? exp2f(S[nt][r]) : 0.f;
                Pc[w][quad * 4 + r][nt * 16 + lq] = f2bf(p);
            }

        short8 pa = *(const short8*)&Pc[w][lq][quad * 8];
#pragma unroll
        for (int dt = 0; dt < 5; dt++) {
            short8 vf = *(const short8*)&Vc[dt * 16 + lq][s_w + quad * 8];
            O[dt] = __builtin_amdgcn_mfma_f32_16x16x32_bf16(pa, vf, O[dt], 0, 0, 0);
        }
    }

    float inv[4];
#pragma unroll
    for (int r = 0; r < 4; r++) {
        float s = __shfl(O[4][r], l & 48);
        inv[r] = 1.0f / s;
    }

#pragma unroll
    for (int dt = 0; dt < 4; dt++)
#pragma unroll
        for (int r = 0; r < 4; r++) {
            int qi = w * 16 + quad * 4 + r;
            int d = dt * 16 + lq;
            float o = O[dt][r] * inv[r];
            ao[((size_t)b * NTOK + h * 64 + qi) * DMODEL + head * HDIM + d] = f2bf(o);
        }
}

// ---------------------------------------------------------------------------
extern "C" void kernel_launch(void* const* d_in, const int* in_sizes, int n_in,
                              void* d_out, int out_size, void* d_ws, size_t ws_size,
                              hipStream_t stream) {
    const float* x      = (const float*)d_in[0];
    const float* w_qkv  = (const float*)d_in[1];
    const float* w_proj = (const float*)d_in[2];
    const float* b_proj = (const float*)d_in[3];
    float* out = (float*)d_out;

    const size_t SZ_X    = (size_t)BATCH * NTOK * DMODEL * 2;
    const size_t SZ_HEAD = (size_t)BH_TOT * NTOK * HDIM * 2;
    char* p = (char*)d_ws;
    short* xb     = (short*)p; p += SZ_X;
    short* wqkvT  = (short*)p; p += (size_t)1536 * 512 * 2;
    short* wprojT = (short*)p; p += (size_t)512 * 512 * 2;
    short* qb     = (short*)p; p += SZ_HEAD;
    short* kb     = (short*)p; p += SZ_HEAD;
    short* vTb    = (short*)p; p += SZ_HEAD;
    short* ao     = xb;  // alias: xb dead after gemm<0>

    cast_x_kernel<<<dim3((BATCH * NTOK * DMODEL) / (256 * 8)), dim3(256), 0, stream>>>(x, xb);
    tcast_kernel<<<dim3(512 / 64, 1536 / 64), dim3(256), 0, stream>>>(w_qkv, wqkvT, 512, 1536);
    tcast_kernel<<<dim3(512 / 64, 512 / 64), dim3(256), 0, stream>>>(w_proj, wprojT, 512, 512);
    gemm_kernel<0><<<dim3(3072), dim3(512), 0, stream>>>(xb, wqkvT, qb, kb, vTb, nullptr, nullptr);
    attn_kernel<<<dim3(HGRID * BH_TOT), dim3(256), 0, stream>>>(qb, kb, vTb, ao);
    gemm_kernel<1><<<dim3(1024), dim3(512), 0, stream>>>(ao, wprojT, nullptr, nullptr, nullptr, out, b_proj);
}